// Round 10
// baseline (892.525 us; speedup 1.0000x reference)
//
#include <hip/hip_runtime.h>

#define B_ 16
#define N_ 4096
#define CIN_ 64
#define COUT_ 128
#define K_ 16
#define M_ 1024

typedef float f32x2 __attribute__((ext_vector_type(2)));
typedef unsigned long long u64;

__device__ __forceinline__ unsigned mono32(float d) {
  unsigned u = __float_as_uint(d);
  return u ^ (unsigned)(((int)u >> 31) | 0x80000000);
}
__device__ __forceinline__ unsigned short f2bf(float x) {
  const unsigned u = __float_as_uint(x);
  return (unsigned short)((u + 0x7FFF + ((u >> 16) & 1)) >> 16);  // RNE
}

// Combined 64-bit wave-max via DPP (values >= 0; bound_ctrl zeros = identity).
#define DPP64(pk, ctrl)                                                        \
  {                                                                            \
    const unsigned lo_ = __builtin_amdgcn_update_dpp(                          \
        0, (int)(unsigned)(pk), ctrl, 0xF, 0xF, true);                         \
    const unsigned hi_ = __builtin_amdgcn_update_dpp(                          \
        0, (int)(unsigned)((pk) >> 32), ctrl, 0xF, 0xF, true);                 \
    const u64 o_ = ((u64)hi_ << 32) | lo_;                                     \
    if (o_ > (pk)) (pk) = o_;                                                  \
  }

// ctrl (float*), zeroed by memset: [0..512) stats sums; byte 2048: prog,
// padded to ONE 64B cache line per batch (prog[b*16]) to avoid cross-XCD
// false sharing between the 16 fps release-stores and ~2048 spinning acquires.
// Roles: [0,16) FPS | [16,528) linear+stats | [528, 528+256*S) one-shot kNN
// split blocks, qt-major (R5/R9-proven).
__global__ __launch_bounds__(512) void mega_kernel(
    const float* __restrict__ pos, const float* __restrict__ features,
    const float* __restrict__ W, const float* __restrict__ bias,
    int* __restrict__ fps_idx, unsigned short* __restrict__ h,
    float* __restrict__ ctrl, u64* __restrict__ cand, int S) {
  __shared__ __align__(16) char smem[84 * 1024];
  const int id = blockIdx.x;
  const int t = threadIdx.x;
  float* stats = ctrl;
  int* prog = (int*)(ctrl + 512);  // prog[b*16]

  if (id < B_) {
    // ---- FPS: 256 lanes, combined u64 DPP reduce + tagged 4-slot spin-poll
    const int b = id;
    float4* P = (float4*)smem;                          // 64 KB
    volatile u64* red = (volatile u64*)(smem + 65536);  // [2][4], tagged
    const float* pb = pos + (size_t)b * N_ * 3;
    if (t < 8) ((u64*)(smem + 65536))[t] = 0;  // tag 0 != any step >= 1
    for (int i = t; i < N_; i += 512)
      P[i] = make_float4(pb[i * 3], pb[i * 3 + 1], pb[i * 3 + 2], 0.f);
    __syncthreads();
    if (t >= 256) return;
    f32x2 px[8], py[8], pz[8], md[8];
#pragma unroll
    for (int j = 0; j < 8; ++j) {
      const float4 lo = P[t + 512 * j];
      const float4 hi = P[t + 512 * j + 256];
      px[j] = (f32x2){lo.x, hi.x};
      py[j] = (f32x2){lo.y, hi.y};
      pz[j] = (f32x2){lo.z, hi.z};
      md[j] = (f32x2){1e10f, 1e10f};
    }
    if (t == 0) fps_idx[b * M_] = 0;
    const int wv = t >> 6;
    const int ln = t & 63;
    const int e0 = 65535 - t;  // enc = 65535 - idx; idx = t + 256*(2j+h)
    float4 lp = P[0];
    for (int step = 1; step < M_; ++step) {
      const f32x2 lx = {lp.x, lp.x}, ly = {lp.y, lp.y}, lz = {lp.z, lp.z};
      float bestd = -1.0f;
      int be = 0;
      {
#pragma clang fp contract(off)
#pragma unroll
        for (int j = 0; j < 8; ++j) {
          const f32x2 dx = px[j] - lx;
          const f32x2 dy = py[j] - ly;
          const f32x2 dz = pz[j] - lz;
          const f32x2 s1 = dx * dx;
          const f32x2 s2 = dy * dy;
          const f32x2 s3 = dz * dz;
          const f32x2 d = (s1 + s2) + s3;  // exact reference order
          f32x2 nd;
          nd.x = fminf(md[j].x, d.x);
          nd.y = fminf(md[j].y, d.y);
          md[j] = nd;
          if (nd.x > bestd) { bestd = nd.x; be = e0 - (j << 9); }
          if (nd.y > bestd) { bestd = nd.y; be = e0 - (j << 9) - 256; }
        }
      }
      // one combined (dist, enc) u64 max chain -> lane 63
      u64 pk = ((u64)__float_as_uint(bestd) << 32) | (unsigned)be;  // be<2^16
      DPP64(pk, 0x111); DPP64(pk, 0x112); DPP64(pk, 0x114); DPP64(pk, 0x118);
      DPP64(pk, 0x142); DPP64(pk, 0x143);
      const u64 wpk =
          ((u64)(unsigned)__builtin_amdgcn_readlane((int)(unsigned)(pk >> 32), 63)
           << 32) |
          (unsigned)__builtin_amdgcn_readlane((int)(unsigned)pk, 63);
      const unsigned tag = (unsigned)(step & 1023);
      volatile u64* rb = red + (step & 1) * 4;
      if (ln == 0) rb[wv] = wpk | ((u64)tag << 16);  // bits16-31 of wpk are 0
      u64 r0, r1, r2, r3;
      for (;;) {
        r0 = rb[0]; r1 = rb[1]; r2 = rb[2]; r3 = rb[3];
        const u64 x = ((r0 >> 16) ^ tag) | ((r1 >> 16) ^ tag) |
                      ((r2 >> 16) ^ tag) | ((r3 >> 16) ^ tag);
        if (!(x & 0x3FF)) break;
      }
      u64 rr = r0 > r1 ? r0 : r1;
      const u64 r2m = r2 > r3 ? r2 : r3;
      if (r2m > rr) rr = r2m;
      const int last = 65535 - (int)(unsigned)(rr & 0xFFFFu);
      lp = P[last];
      if (t == 0) {
        fps_idx[b * M_ + step] = last;
        if ((step & 63) == 63)
          __hip_atomic_store(&prog[b * 16], (step >> 6) + 1, __ATOMIC_RELEASE,
                             __HIP_MEMORY_SCOPE_AGENT);
      }
    }
    return;
  }

  if (id < B_ + 512) {
    // ---------------- linear (h bf16) + stats partials ----------------
    const int lid = id - B_;
    float* ls = (float*)smem;  // 256 floats
    for (int i = t; i < 256; i += 512) ls[i] = 0.f;
    __syncthreads();
    const int o4 = (t & 31) << 2;
    const int rl = t >> 5;
    const float4 bv = *(const float4*)(bias + o4);
    float4 s4 = {0, 0, 0, 0}, ss4 = {0, 0, 0, 0};
    for (int i = 0; i < 8; ++i) {
      const int r = lid * 128 + rl * 8 + i;
      const float4* fr = (const float4*)(features + (size_t)r * CIN_);
      float4 acc = bv;
#pragma unroll
      for (int c4 = 0; c4 < 16; ++c4) {
        const float4 fv = fr[c4];
        const float* wr = W + (size_t)(c4 * 4) * COUT_ + o4;
        const float4 w0 = *(const float4*)(wr);
        const float4 w1 = *(const float4*)(wr + COUT_);
        const float4 w2 = *(const float4*)(wr + 2 * COUT_);
        const float4 w3 = *(const float4*)(wr + 3 * COUT_);
        acc.x = fmaf(fv.x, w0.x, acc.x); acc.y = fmaf(fv.x, w0.y, acc.y);
        acc.z = fmaf(fv.x, w0.z, acc.z); acc.w = fmaf(fv.x, w0.w, acc.w);
        acc.x = fmaf(fv.y, w1.x, acc.x); acc.y = fmaf(fv.y, w1.y, acc.y);
        acc.z = fmaf(fv.y, w1.z, acc.z); acc.w = fmaf(fv.y, w1.w, acc.w);
        acc.x = fmaf(fv.z, w2.x, acc.x); acc.y = fmaf(fv.z, w2.y, acc.y);
        acc.z = fmaf(fv.z, w2.z, acc.z); acc.w = fmaf(fv.z, w2.w, acc.w);
        acc.x = fmaf(fv.w, w3.x, acc.x); acc.y = fmaf(fv.w, w3.y, acc.y);
        acc.z = fmaf(fv.w, w3.z, acc.z); acc.w = fmaf(fv.w, w3.w, acc.w);
      }
      *(ushort4*)(h + (size_t)r * COUT_ + o4) =
          make_ushort4(f2bf(acc.x), f2bf(acc.y), f2bf(acc.z), f2bf(acc.w));
      s4.x += acc.x; s4.y += acc.y; s4.z += acc.z; s4.w += acc.w;
      ss4.x = fmaf(acc.x, acc.x, ss4.x); ss4.y = fmaf(acc.y, acc.y, ss4.y);
      ss4.z = fmaf(acc.z, acc.z, ss4.z); ss4.w = fmaf(acc.w, acc.w, ss4.w);
    }
    atomicAdd(&ls[o4 + 0], s4.x); atomicAdd(&ls[o4 + 1], s4.y);
    atomicAdd(&ls[o4 + 2], s4.z); atomicAdd(&ls[o4 + 3], s4.w);
    atomicAdd(&ls[128 + o4 + 0], ss4.x); atomicAdd(&ls[128 + o4 + 1], ss4.y);
    atomicAdd(&ls[128 + o4 + 2], ss4.z); atomicAdd(&ls[128 + o4 + 3], ss4.w);
    __syncthreads();
    if (t < 128) {
      atomicAdd(&stats[t], ls[t]);
      atomicAdd(&stats[128 + t], ls[128 + t]);
    }
    return;
  }

  // ------------------- one-shot kNN split block (R5/R9-proven) --------------
  {
    const int kid = id - (B_ + 512);
    const int qt = kid / (B_ * S);
    const int rem = kid % (B_ * S);
    const int b = rem / S;
    const int s = rem % S;
    const int KPS = N_ / S;
    const int KT = KPS / 128;
    float* Qs = (float*)smem;
    float* Ks = (float*)(smem + 16384);
    float* sd2 = (float*)(smem + 49152);
    float* qq = (float*)(smem + 82944);
    float* ff = (float*)(smem + 83200);
    int* qid = (int*)(smem + 83712);
    const float* fb = features + (size_t)b * N_ * CIN_;

    if (t == 0) {
      while (__hip_atomic_load(&prog[b * 16], __ATOMIC_ACQUIRE,
                               __HIP_MEMORY_SCOPE_AGENT) < qt + 1)
        __builtin_amdgcn_s_sleep(16);
    }
    __syncthreads();
    if (t < 64) qid[t] = fps_idx[b * M_ + qt * 64 + t];
    __syncthreads();
#pragma unroll
    for (int st = 0; st < 2; ++st) {
      const int iid = t + 512 * st;
      const int row = iid >> 4, c4 = iid & 15;
      const int pc = (c4 + (row >> 2)) & 15;
      const float4 v = *(const float4*)(fb + (size_t)qid[row] * CIN_ + c4 * 4);
      *(float4*)(&Qs[row * 64 + pc * 4]) = v;
    }
    __syncthreads();
    if (t < 64) {
      float sv = 0.f;
#pragma unroll
      for (int c4 = 0; c4 < 16; ++c4) {
        const int pc = (c4 + (t >> 2)) & 15;
        const float4 v = *(const float4*)(&Qs[t * 64 + pc * 4]);
        sv = fmaf(v.x, v.x, sv); sv = fmaf(v.y, v.y, sv);
        sv = fmaf(v.z, v.z, sv); sv = fmaf(v.w, v.w, sv);
      }
      qq[t] = sv;
    }

    u64 lst[16];
#pragma unroll
    for (int p = 0; p < 16; ++p) lst[p] = ~0ull;
    u64 worst = ~0ull;
    int wpos = 0;

    const int q0 = (t >> 5) * 4;
    const int k0 = (t & 31) * 4;
    const int sq = t >> 3;
    const int ssub = t & 7;

    for (int kt = 0; kt < KT; ++kt) {
      const int kb = s * KPS + kt * 128;
#pragma unroll
      for (int st = 0; st < 4; ++st) {
        const int iid = t + 512 * st;
        const int row = iid >> 4, c4 = iid & 15;
        const int pc = (c4 + (row >> 2)) & 15;
        const float4 v =
            *(const float4*)(fb + (size_t)(kb + row) * CIN_ + c4 * 4);
        *(float4*)(&Ks[row * 64 + pc * 4]) = v;
      }
      __syncthreads();
      if (t < 128) {
        float sv = 0.f;
#pragma unroll
        for (int c4 = 0; c4 < 16; ++c4) {
          const int pc = (c4 + (t >> 2)) & 15;
          const float4 v = *(const float4*)(&Ks[t * 64 + pc * 4]);
          sv = fmaf(v.x, v.x, sv); sv = fmaf(v.y, v.y, sv);
          sv = fmaf(v.z, v.z, sv); sv = fmaf(v.w, v.w, sv);
        }
        ff[t] = sv;
      }
      __syncthreads();
      float acc[4][4];
#pragma unroll
      for (int i = 0; i < 4; ++i)
#pragma unroll
        for (int j = 0; j < 4; ++j) acc[i][j] = 0.f;
#pragma unroll
      for (int c4 = 0; c4 < 16; ++c4) {
        float4 qv[4], kv[4];
#pragma unroll
        for (int i = 0; i < 4; ++i) {
          const int row = q0 + i;
          const int pc = (c4 + (row >> 2)) & 15;
          qv[i] = *(const float4*)(&Qs[row * 64 + pc * 4]);
        }
#pragma unroll
        for (int j = 0; j < 4; ++j) {
          const int row = k0 + j;
          const int pc = (c4 + (row >> 2)) & 15;
          kv[j] = *(const float4*)(&Ks[row * 64 + pc * 4]);
        }
#pragma unroll
        for (int i = 0; i < 4; ++i)
#pragma unroll
          for (int j = 0; j < 4; ++j) {
            acc[i][j] = fmaf(qv[i].x, kv[j].x, acc[i][j]);
            acc[i][j] = fmaf(qv[i].y, kv[j].y, acc[i][j]);
            acc[i][j] = fmaf(qv[i].z, kv[j].z, acc[i][j]);
            acc[i][j] = fmaf(qv[i].w, kv[j].w, acc[i][j]);
          }
      }
#pragma unroll
      for (int i = 0; i < 4; ++i) {
        const float qv = qq[q0 + i];
        float4 o;
        o.x = __fsub_rn(__fadd_rn(qv, ff[k0 + 0]), 2.f * acc[i][0]);
        o.y = __fsub_rn(__fadd_rn(qv, ff[k0 + 1]), 2.f * acc[i][1]);
        o.z = __fsub_rn(__fadd_rn(qv, ff[k0 + 2]), 2.f * acc[i][2]);
        o.w = __fsub_rn(__fadd_rn(qv, ff[k0 + 3]), 2.f * acc[i][3]);
        *(float4*)(&sd2[(q0 + i) * 132 + k0]) = o;
      }
      __syncthreads();
#pragma unroll
      for (int g = 0; g < 4; ++g) {
        const float4 v = *(const float4*)(&sd2[sq * 132 + ssub * 16 + g * 4]);
        const float dv[4] = {v.x, v.y, v.z, v.w};
#pragma unroll
        for (int jj = 0; jj < 4; ++jj) {
          const int key = kb + ssub * 16 + g * 4 + jj;
          const u64 pk = ((u64)mono32(dv[jj]) << 32) | (unsigned)key;
          if (pk < worst) {
#pragma unroll
            for (int p = 0; p < 16; ++p)
              if (p == wpos) lst[p] = pk;
            worst = lst[0]; wpos = 0;
#pragma unroll
            for (int p = 1; p < 16; ++p)
              if (lst[p] > worst) { worst = lst[p]; wpos = p; }
          }
        }
      }
      __syncthreads();
    }
    u64* cb = cand + ((size_t)(b * M_ + qt * 64 + sq) * S + s) * 16;
    for (int r = 0; r < K_; ++r) {
      u64 mn = lst[0];
#pragma unroll
      for (int p = 1; p < 16; ++p)
        if (lst[p] < mn) mn = lst[p];
      u64 m2 = mn;
#pragma unroll
      for (int off = 1; off < 8; off <<= 1) {
        const u64 o = __shfl_xor(m2, off, 64);
        if (o < m2) m2 = o;
      }
      if (mn == m2) {
        bool done = false;
#pragma unroll
        for (int p = 0; p < 16; ++p)
          if (!done && lst[p] == m2) { lst[p] = ~0ull; done = true; }
      }
      if (ssub == 0) cb[r] = m2;
    }
  }
}

// Tile-based (R8-proven): 256 merge/gather blocks + 16 tail blocks.
__global__ __launch_bounds__(256) void gather_tail_kernel(
    const float* __restrict__ pos, const int* __restrict__ fps_idx,
    const unsigned short* __restrict__ h, const float* __restrict__ ctrl,
    const float* __restrict__ gamma, const float* __restrict__ beta,
    const u64* __restrict__ cand, float* __restrict__ out, int S,
    int batch_as_i64) {
  const int g = blockIdx.x;
  const int t = threadIdx.x;
  const int A = B_ * M_ * COUT_;
  const int P = B_ * M_ * 3;
  if (g >= 256) {  // tail blocks
    const int gid2 = (g - 256) * 256 + t;
    for (int i = 0; i < 16; ++i) {
      const int gid = gid2 + 4096 * i;
      if (gid < P) {
        const int Q = gid / 3;
        const int c = gid - Q * 3;
        const int b = Q >> 10;
        const int idx = fps_idx[Q];
        out[A + gid] = pos[((size_t)b * N_ + idx) * 3 + c];
      } else {
        const int Q = gid - P;
        if (Q < B_ * M_) {
          const int b = Q >> 10;
          float* base = out + A + P;
          if (batch_as_i64)
            ((long long*)base)[Q] = (long long)b;
          else
            base[Q] = (float)b;
        }
      }
    }
    return;
  }
  __shared__ u64 cl[64 * 128];  // 64 queries x (S*16 <= 128)
  __shared__ int nbi[64 * 16];
  __shared__ float scsh[256];
  const int b = g >> 4, qt = g & 15;
  if (t < 128) {
    const float inv = 1.0f / (float)(B_ * N_);
    const float mean = ctrl[t] * inv;
    const float var = ctrl[128 + t] * inv - mean * mean;
    const float r = 1.0f / sqrtf(var + 1e-5f);
    const float sc = gamma[t] * r;
    scsh[t] = sc;
    scsh[128 + t] = beta[t] - mean * sc;
  }
  const int S16 = S * 16;
  const u64* cg = cand + (size_t)(b * M_ + qt * 64) * S16;
  for (int i = t; i < 64 * S16; i += 256) cl[i] = cg[i];
  __syncthreads();
  if (t < 64) {  // exact S-way sorted merge, query t
    int ptr[8] = {0, 0, 0, 0, 0, 0, 0, 0};
    for (int r = 0; r < K_; ++r) {
      u64 mn = ~0ull;
      int ms = 0;
      for (int s = 0; s < S; ++s) {
        if (ptr[s] < 16) {
          const u64 v = cl[t * S16 + s * 16 + ptr[s]];
          if (v < mn) { mn = v; ms = s; }
        }
      }
      nbi[t * 16 + r] = (int)(unsigned)(mn & 0xFFFFFFFFu);
      ptr[ms]++;
    }
  }
  __syncthreads();
  // gather: 4 lanes/query x 32 channels; min+max so BN sign is safe post-pool
  const int q = t >> 2;
  const int c0 = (t & 3) * 32;
  float mx[32], mn[32];
#pragma unroll
  for (int i = 0; i < 32; ++i) { mx[i] = -3.402823466e38f; mn[i] = 3.402823466e38f; }
#pragma unroll
  for (int k = 0; k < K_; ++k) {
    const int n = nbi[q * 16 + k];
    const uint4* hr = (const uint4*)(h + ((size_t)b * N_ + n) * COUT_ + c0);
#pragma unroll
    for (int j = 0; j < 4; ++j) {
      const uint4 hv = hr[j];
      const unsigned hu[4] = {hv.x, hv.y, hv.z, hv.w};
#pragma unroll
      for (int i = 0; i < 4; ++i) {
        const float lo = __uint_as_float(hu[i] << 16);
        const float hi = __uint_as_float(hu[i] & 0xFFFF0000u);
        const int c = j * 8 + 2 * i;
        mx[c] = fmaxf(mx[c], lo); mn[c] = fminf(mn[c], lo);
        mx[c + 1] = fmaxf(mx[c + 1], hi); mn[c + 1] = fminf(mn[c + 1], hi);
      }
    }
  }
  float* ob = out + (size_t)(b * M_ + qt * 64 + q) * COUT_ + c0;
#pragma unroll
  for (int i = 0; i < 8; ++i) {
    float4 o;
#pragma unroll
    for (int e = 0; e < 4; ++e) {
      const int c = 4 * i + e;
      const float sc = scsh[c0 + c], sh = scsh[128 + c0 + c];
      const float v = sc >= 0.f ? mx[c] : mn[c];
      (&o.x)[e] = fmaf(v, sc, sh);
    }
    *(float4*)(ob + 4 * i) = o;
  }
}

extern "C" void kernel_launch(void* const* d_in, const int* in_sizes, int n_in,
                              void* d_out, int out_size, void* d_ws, size_t ws_size,
                              hipStream_t stream) {
  const float* features = (const float*)d_in[0];
  const float* positions = (const float*)d_in[1];
  const float* W = (const float*)d_in[3];
  const float* bias = (const float*)d_in[4];
  const float* gamma = (const float*)d_in[5];
  const float* beta = (const float*)d_in[6];
  float* out = (float*)d_out;
  unsigned char* ws = (unsigned char*)d_ws;

  int* fps_idx = (int*)ws;                            // 64 KB
  unsigned short* h = (unsigned short*)(ws + 65536);  // bf16, 16.8 MB
  const size_t hoff = 65536 + (size_t)B_ * N_ * COUT_ * 2;
  float* ctrl = (float*)(ws + hoff);                  // 4 KB
  u64* cand = (u64*)(ws + hoff + 4096);
  const size_t base = hoff + 4096;

  int S = 8;
  while (S > 1 && base + (size_t)B_ * M_ * S * 16 * 8 > ws_size) S >>= 1;

  const int rem = out_size - (B_ * M_ * COUT_) - (B_ * M_ * 3);
  const int batch_as_i64 = (rem >= 2 * B_ * M_) ? 1 : 0;

  hipMemsetAsync(ctrl, 0, 4096, stream);
  mega_kernel<<<B_ + 512 + 256 * S, 512, 0, stream>>>(
      positions, features, W, bias, fps_idx, h, ctrl, cand, S);
  gather_tail_kernel<<<256 + 16, 256, 0, stream>>>(
      positions, fps_idx, h, ctrl, gamma, beta, cand, out, S, batch_as_i64);
}

// Round 11
// 888.515 us; speedup vs baseline: 1.0045x; 1.0045x over previous
//
#include <hip/hip_runtime.h>

#define B_ 16
#define N_ 4096
#define CIN_ 64
#define COUT_ 128
#define K_ 16
#define M_ 1024

typedef float f32x2 __attribute__((ext_vector_type(2)));
typedef unsigned long long u64;

__device__ __forceinline__ unsigned mono32(float d) {
  unsigned u = __float_as_uint(d);
  return u ^ (unsigned)(((int)u >> 31) | 0x80000000);
}
__device__ __forceinline__ unsigned short f2bf(float x) {
  const unsigned u = __float_as_uint(x);
  return (unsigned short)((u + 0x7FFF + ((u >> 16) & 1)) >> 16);  // RNE
}

// Combined 64-bit wave-max via DPP (values >= 0; bound_ctrl zeros = identity).
#define DPP64(pk, ctrl)                                                        \
  {                                                                            \
    const unsigned lo_ = __builtin_amdgcn_update_dpp(                          \
        0, (int)(unsigned)(pk), ctrl, 0xF, 0xF, true);                         \
    const unsigned hi_ = __builtin_amdgcn_update_dpp(                          \
        0, (int)(unsigned)((pk) >> 32), ctrl, 0xF, 0xF, true);                 \
    const u64 o_ = ((u64)hi_ << 32) | lo_;                                     \
    if (o_ > (pk)) (pk) = o_;                                                  \
  }

// ctrl (float*), zeroed by memset: [0..512) stats sums; byte 2048: prog,
// one 64B line per batch (prog[b*16]).
// Roles: [0,16) FPS | [16,528) linear+stats | [528, 528+256*S) one-shot kNN
// split blocks, qt-major (R5/R9-proven).
__global__ __launch_bounds__(512) void mega_kernel(
    const float* __restrict__ pos, const float* __restrict__ features,
    const float* __restrict__ W, const float* __restrict__ bias,
    int* __restrict__ fps_idx, unsigned short* __restrict__ h,
    float* __restrict__ ctrl, u64* __restrict__ cand, int S) {
  __shared__ __align__(16) char smem[84 * 1024];
  const int id = blockIdx.x;
  const int t = threadIdx.x;
  float* stats = ctrl;
  int* prog = (int*)(ctrl + 512);  // prog[b*16]

  if (id < B_) {
    // ---- FPS: 256 lanes, combined u64 DPP reduce + tagged 4-slot spin-poll.
    // Poll reads the 4 slots as TWO pipelined b128 loads (non-volatile) with
    // an asm memory clobber to force re-read — avoids serialized volatile
    // ds_read_b64 + per-load waits on the critical path.
    const int b = id;
    float4* P = (float4*)smem;            // 64 KB
    u64* red = (u64*)(smem + 65536);      // [2][4], tagged
    const float* pb = pos + (size_t)b * N_ * 3;
    if (t < 8) red[t] = 0;  // tag 0 != any step >= 1
    for (int i = t; i < N_; i += 512)
      P[i] = make_float4(pb[i * 3], pb[i * 3 + 1], pb[i * 3 + 2], 0.f);
    __syncthreads();
    if (t >= 256) return;
    f32x2 px[8], py[8], pz[8], md[8];
#pragma unroll
    for (int j = 0; j < 8; ++j) {
      const float4 lo = P[t + 512 * j];
      const float4 hi = P[t + 512 * j + 256];
      px[j] = (f32x2){lo.x, hi.x};
      py[j] = (f32x2){lo.y, hi.y};
      pz[j] = (f32x2){lo.z, hi.z};
      md[j] = (f32x2){1e10f, 1e10f};
    }
    if (t == 0) fps_idx[b * M_] = 0;
    const int wv = t >> 6;
    const int ln = t & 63;
    const int e0 = 65535 - t;  // enc = 65535 - idx; idx = t + 256*(2j+h)
    float4 lp = P[0];
    for (int step = 1; step < M_; ++step) {
      const f32x2 lx = {lp.x, lp.x}, ly = {lp.y, lp.y}, lz = {lp.z, lp.z};
      float bestd = -1.0f;
      int be = 0;
      {
#pragma clang fp contract(off)
#pragma unroll
        for (int j = 0; j < 8; ++j) {
          const f32x2 dx = px[j] - lx;
          const f32x2 dy = py[j] - ly;
          const f32x2 dz = pz[j] - lz;
          const f32x2 s1 = dx * dx;
          const f32x2 s2 = dy * dy;
          const f32x2 s3 = dz * dz;
          const f32x2 d = (s1 + s2) + s3;  // exact reference order
          f32x2 nd;
          nd.x = fminf(md[j].x, d.x);
          nd.y = fminf(md[j].y, d.y);
          md[j] = nd;
          if (nd.x > bestd) { bestd = nd.x; be = e0 - (j << 9); }
          if (nd.y > bestd) { bestd = nd.y; be = e0 - (j << 9) - 256; }
        }
      }
      // one combined (dist, enc) u64 max chain -> lane 63
      u64 pk = ((u64)__float_as_uint(bestd) << 32) | (unsigned)be;  // be<2^16
      DPP64(pk, 0x111); DPP64(pk, 0x112); DPP64(pk, 0x114); DPP64(pk, 0x118);
      DPP64(pk, 0x142); DPP64(pk, 0x143);
      const u64 wpk =
          ((u64)(unsigned)__builtin_amdgcn_readlane((int)(unsigned)(pk >> 32), 63)
           << 32) |
          (unsigned)__builtin_amdgcn_readlane((int)(unsigned)pk, 63);
      const unsigned tag = (unsigned)(step & 1023);
      u64* rb = red + (step & 1) * 4;
      if (ln == 0) rb[wv] = wpk | ((u64)tag << 16);  // bits16-31 of wpk are 0
      __asm__ __volatile__("" ::: "memory");         // force store issue
      u64 r0, r1, r2, r3;
      for (;;) {
        const ulonglong2 a = *(const ulonglong2*)&rb[0];  // pipelined b128
        const ulonglong2 c = *(const ulonglong2*)&rb[2];
        r0 = a.x; r1 = a.y; r2 = c.x; r3 = c.y;
        const u64 x = ((r0 >> 16) ^ tag) | ((r1 >> 16) ^ tag) |
                      ((r2 >> 16) ^ tag) | ((r3 >> 16) ^ tag);
        if (!(x & 0x3FF)) break;
        __asm__ __volatile__("" ::: "memory");  // re-read next iteration
      }
      u64 rr = r0 > r1 ? r0 : r1;
      const u64 r2m = r2 > r3 ? r2 : r3;
      if (r2m > rr) rr = r2m;
      const int last = 65535 - (int)(unsigned)(rr & 0xFFFFu);
      lp = P[last];
      if (t == 0) {
        fps_idx[b * M_ + step] = last;
        if ((step & 63) == 63)
          __hip_atomic_store(&prog[b * 16], (step >> 6) + 1, __ATOMIC_RELEASE,
                             __HIP_MEMORY_SCOPE_AGENT);
      }
    }
    return;
  }

  if (id < B_ + 512) {
    // ---------------- linear (h bf16) + stats partials ----------------
    const int lid = id - B_;
    float* ls = (float*)smem;  // 256 floats
    for (int i = t; i < 256; i += 512) ls[i] = 0.f;
    __syncthreads();
    const int o4 = (t & 31) << 2;
    const int rl = t >> 5;
    const float4 bv = *(const float4*)(bias + o4);
    float4 s4 = {0, 0, 0, 0}, ss4 = {0, 0, 0, 0};
    for (int i = 0; i < 8; ++i) {
      const int r = lid * 128 + rl * 8 + i;
      const float4* fr = (const float4*)(features + (size_t)r * CIN_);
      float4 acc = bv;
#pragma unroll
      for (int c4 = 0; c4 < 16; ++c4) {
        const float4 fv = fr[c4];
        const float* wr = W + (size_t)(c4 * 4) * COUT_ + o4;
        const float4 w0 = *(const float4*)(wr);
        const float4 w1 = *(const float4*)(wr + COUT_);
        const float4 w2 = *(const float4*)(wr + 2 * COUT_);
        const float4 w3 = *(const float4*)(wr + 3 * COUT_);
        acc.x = fmaf(fv.x, w0.x, acc.x); acc.y = fmaf(fv.x, w0.y, acc.y);
        acc.z = fmaf(fv.x, w0.z, acc.z); acc.w = fmaf(fv.x, w0.w, acc.w);
        acc.x = fmaf(fv.y, w1.x, acc.x); acc.y = fmaf(fv.y, w1.y, acc.y);
        acc.z = fmaf(fv.y, w1.z, acc.z); acc.w = fmaf(fv.y, w1.w, acc.w);
        acc.x = fmaf(fv.z, w2.x, acc.x); acc.y = fmaf(fv.z, w2.y, acc.y);
        acc.z = fmaf(fv.z, w2.z, acc.z); acc.w = fmaf(fv.z, w2.w, acc.w);
        acc.x = fmaf(fv.w, w3.x, acc.x); acc.y = fmaf(fv.w, w3.y, acc.y);
        acc.z = fmaf(fv.w, w3.z, acc.z); acc.w = fmaf(fv.w, w3.w, acc.w);
      }
      *(ushort4*)(h + (size_t)r * COUT_ + o4) =
          make_ushort4(f2bf(acc.x), f2bf(acc.y), f2bf(acc.z), f2bf(acc.w));
      s4.x += acc.x; s4.y += acc.y; s4.z += acc.z; s4.w += acc.w;
      ss4.x = fmaf(acc.x, acc.x, ss4.x); ss4.y = fmaf(acc.y, acc.y, ss4.y);
      ss4.z = fmaf(acc.z, acc.z, ss4.z); ss4.w = fmaf(acc.w, acc.w, ss4.w);
    }
    atomicAdd(&ls[o4 + 0], s4.x); atomicAdd(&ls[o4 + 1], s4.y);
    atomicAdd(&ls[o4 + 2], s4.z); atomicAdd(&ls[o4 + 3], s4.w);
    atomicAdd(&ls[128 + o4 + 0], ss4.x); atomicAdd(&ls[128 + o4 + 1], ss4.y);
    atomicAdd(&ls[128 + o4 + 2], ss4.z); atomicAdd(&ls[128 + o4 + 3], ss4.w);
    __syncthreads();
    if (t < 128) {
      atomicAdd(&stats[t], ls[t]);
      atomicAdd(&stats[128 + t], ls[128 + t]);
    }
    return;
  }

  // ------------------- one-shot kNN split block (R5/R9-proven) --------------
  {
    const int kid = id - (B_ + 512);
    const int qt = kid / (B_ * S);
    const int rem = kid % (B_ * S);
    const int b = rem / S;
    const int s = rem % S;
    const int KPS = N_ / S;
    const int KT = KPS / 128;
    float* Qs = (float*)smem;
    float* Ks = (float*)(smem + 16384);
    float* sd2 = (float*)(smem + 49152);
    float* qq = (float*)(smem + 82944);
    float* ff = (float*)(smem + 83200);
    int* qid = (int*)(smem + 83712);
    const float* fb = features + (size_t)b * N_ * CIN_;

    if (t == 0) {
      while (__hip_atomic_load(&prog[b * 16], __ATOMIC_ACQUIRE,
                               __HIP_MEMORY_SCOPE_AGENT) < qt + 1)
        __builtin_amdgcn_s_sleep(16);
    }
    __syncthreads();
    if (t < 64) qid[t] = fps_idx[b * M_ + qt * 64 + t];
    __syncthreads();
#pragma unroll
    for (int st = 0; st < 2; ++st) {
      const int iid = t + 512 * st;
      const int row = iid >> 4, c4 = iid & 15;
      const int pc = (c4 + (row >> 2)) & 15;
      const float4 v = *(const float4*)(fb + (size_t)qid[row] * CIN_ + c4 * 4);
      *(float4*)(&Qs[row * 64 + pc * 4]) = v;
    }
    __syncthreads();
    if (t < 64) {
      float sv = 0.f;
#pragma unroll
      for (int c4 = 0; c4 < 16; ++c4) {
        const int pc = (c4 + (t >> 2)) & 15;
        const float4 v = *(const float4*)(&Qs[t * 64 + pc * 4]);
        sv = fmaf(v.x, v.x, sv); sv = fmaf(v.y, v.y, sv);
        sv = fmaf(v.z, v.z, sv); sv = fmaf(v.w, v.w, sv);
      }
      qq[t] = sv;
    }

    u64 lst[16];
#pragma unroll
    for (int p = 0; p < 16; ++p) lst[p] = ~0ull;
    u64 worst = ~0ull;
    int wpos = 0;

    const int q0 = (t >> 5) * 4;
    const int k0 = (t & 31) * 4;
    const int sq = t >> 3;
    const int ssub = t & 7;

    for (int kt = 0; kt < KT; ++kt) {
      const int kb = s * KPS + kt * 128;
#pragma unroll
      for (int st = 0; st < 4; ++st) {
        const int iid = t + 512 * st;
        const int row = iid >> 4, c4 = iid & 15;
        const int pc = (c4 + (row >> 2)) & 15;
        const float4 v =
            *(const float4*)(fb + (size_t)(kb + row) * CIN_ + c4 * 4);
        *(float4*)(&Ks[row * 64 + pc * 4]) = v;
      }
      __syncthreads();
      if (t < 128) {
        float sv = 0.f;
#pragma unroll
        for (int c4 = 0; c4 < 16; ++c4) {
          const int pc = (c4 + (t >> 2)) & 15;
          const float4 v = *(const float4*)(&Ks[t * 64 + pc * 4]);
          sv = fmaf(v.x, v.x, sv); sv = fmaf(v.y, v.y, sv);
          sv = fmaf(v.z, v.z, sv); sv = fmaf(v.w, v.w, sv);
        }
        ff[t] = sv;
      }
      __syncthreads();
      float acc[4][4];
#pragma unroll
      for (int i = 0; i < 4; ++i)
#pragma unroll
        for (int j = 0; j < 4; ++j) acc[i][j] = 0.f;
#pragma unroll
      for (int c4 = 0; c4 < 16; ++c4) {
        float4 qv[4], kv[4];
#pragma unroll
        for (int i = 0; i < 4; ++i) {
          const int row = q0 + i;
          const int pc = (c4 + (row >> 2)) & 15;
          qv[i] = *(const float4*)(&Qs[row * 64 + pc * 4]);
        }
#pragma unroll
        for (int j = 0; j < 4; ++j) {
          const int row = k0 + j;
          const int pc = (c4 + (row >> 2)) & 15;
          kv[j] = *(const float4*)(&Ks[row * 64 + pc * 4]);
        }
#pragma unroll
        for (int i = 0; i < 4; ++i)
#pragma unroll
          for (int j = 0; j < 4; ++j) {
            acc[i][j] = fmaf(qv[i].x, kv[j].x, acc[i][j]);
            acc[i][j] = fmaf(qv[i].y, kv[j].y, acc[i][j]);
            acc[i][j] = fmaf(qv[i].z, kv[j].z, acc[i][j]);
            acc[i][j] = fmaf(qv[i].w, kv[j].w, acc[i][j]);
          }
      }
#pragma unroll
      for (int i = 0; i < 4; ++i) {
        const float qv = qq[q0 + i];
        float4 o;
        o.x = __fsub_rn(__fadd_rn(qv, ff[k0 + 0]), 2.f * acc[i][0]);
        o.y = __fsub_rn(__fadd_rn(qv, ff[k0 + 1]), 2.f * acc[i][1]);
        o.z = __fsub_rn(__fadd_rn(qv, ff[k0 + 2]), 2.f * acc[i][2]);
        o.w = __fsub_rn(__fadd_rn(qv, ff[k0 + 3]), 2.f * acc[i][3]);
        *(float4*)(&sd2[(q0 + i) * 132 + k0]) = o;
      }
      __syncthreads();
#pragma unroll
      for (int g = 0; g < 4; ++g) {
        const float4 v = *(const float4*)(&sd2[sq * 132 + ssub * 16 + g * 4]);
        const float dv[4] = {v.x, v.y, v.z, v.w};
#pragma unroll
        for (int jj = 0; jj < 4; ++jj) {
          const int key = kb + ssub * 16 + g * 4 + jj;
          const u64 pk = ((u64)mono32(dv[jj]) << 32) | (unsigned)key;
          if (pk < worst) {
#pragma unroll
            for (int p = 0; p < 16; ++p)
              if (p == wpos) lst[p] = pk;
            worst = lst[0]; wpos = 0;
#pragma unroll
            for (int p = 1; p < 16; ++p)
              if (lst[p] > worst) { worst = lst[p]; wpos = p; }
          }
        }
      }
      __syncthreads();
    }
    u64* cb = cand + ((size_t)(b * M_ + qt * 64 + sq) * S + s) * 16;
    for (int r = 0; r < K_; ++r) {
      u64 mn = lst[0];
#pragma unroll
      for (int p = 1; p < 16; ++p)
        if (lst[p] < mn) mn = lst[p];
      u64 m2 = mn;
#pragma unroll
      for (int off = 1; off < 8; off <<= 1) {
        const u64 o = __shfl_xor(m2, off, 64);
        if (o < m2) m2 = o;
      }
      if (mn == m2) {
        bool done = false;
#pragma unroll
        for (int p = 0; p < 16; ++p)
          if (!done && lst[p] == m2) { lst[p] = ~0ull; done = true; }
      }
      if (ssub == 0) cb[r] = m2;
    }
  }
}

// Tile-based (R8-proven): 256 merge/gather blocks + 16 tail blocks.
__global__ __launch_bounds__(256) void gather_tail_kernel(
    const float* __restrict__ pos, const int* __restrict__ fps_idx,
    const unsigned short* __restrict__ h, const float* __restrict__ ctrl,
    const float* __restrict__ gamma, const float* __restrict__ beta,
    const u64* __restrict__ cand, float* __restrict__ out, int S,
    int batch_as_i64) {
  const int g = blockIdx.x;
  const int t = threadIdx.x;
  const int A = B_ * M_ * COUT_;
  const int P = B_ * M_ * 3;
  if (g >= 256) {  // tail blocks
    const int gid2 = (g - 256) * 256 + t;
    for (int i = 0; i < 16; ++i) {
      const int gid = gid2 + 4096 * i;
      if (gid < P) {
        const int Q = gid / 3;
        const int c = gid - Q * 3;
        const int b = Q >> 10;
        const int idx = fps_idx[Q];
        out[A + gid] = pos[((size_t)b * N_ + idx) * 3 + c];
      } else {
        const int Q = gid - P;
        if (Q < B_ * M_) {
          const int b = Q >> 10;
          float* base = out + A + P;
          if (batch_as_i64)
            ((long long*)base)[Q] = (long long)b;
          else
            base[Q] = (float)b;
        }
      }
    }
    return;
  }
  __shared__ u64 cl[64 * 128];  // 64 queries x (S*16 <= 128)
  __shared__ int nbi[64 * 16];
  __shared__ float scsh[256];
  const int b = g >> 4, qt = g & 15;
  if (t < 128) {
    const float inv = 1.0f / (float)(B_ * N_);
    const float mean = ctrl[t] * inv;
    const float var = ctrl[128 + t] * inv - mean * mean;
    const float r = 1.0f / sqrtf(var + 1e-5f);
    const float sc = gamma[t] * r;
    scsh[t] = sc;
    scsh[128 + t] = beta[t] - mean * sc;
  }
  const int S16 = S * 16;
  const u64* cg = cand + (size_t)(b * M_ + qt * 64) * S16;
  for (int i = t; i < 64 * S16; i += 256) cl[i] = cg[i];
  __syncthreads();
  if (t < 64) {  // exact S-way sorted merge, query t
    int ptr[8] = {0, 0, 0, 0, 0, 0, 0, 0};
    for (int r = 0; r < K_; ++r) {
      u64 mn = ~0ull;
      int ms = 0;
      for (int s = 0; s < S; ++s) {
        if (ptr[s] < 16) {
          const u64 v = cl[t * S16 + s * 16 + ptr[s]];
          if (v < mn) { mn = v; ms = s; }
        }
      }
      nbi[t * 16 + r] = (int)(unsigned)(mn & 0xFFFFFFFFu);
      ptr[ms]++;
    }
  }
  __syncthreads();
  // gather: 4 lanes/query x 32 channels; min+max so BN sign is safe post-pool
  const int q = t >> 2;
  const int c0 = (t & 3) * 32;
  float mx[32], mn[32];
#pragma unroll
  for (int i = 0; i < 32; ++i) { mx[i] = -3.402823466e38f; mn[i] = 3.402823466e38f; }
#pragma unroll
  for (int k = 0; k < K_; ++k) {
    const int n = nbi[q * 16 + k];
    const uint4* hr = (const uint4*)(h + ((size_t)b * N_ + n) * COUT_ + c0);
#pragma unroll
    for (int j = 0; j < 4; ++j) {
      const uint4 hv = hr[j];
      const unsigned hu[4] = {hv.x, hv.y, hv.z, hv.w};
#pragma unroll
      for (int i = 0; i < 4; ++i) {
        const float lo = __uint_as_float(hu[i] << 16);
        const float hi = __uint_as_float(hu[i] & 0xFFFF0000u);
        const int c = j * 8 + 2 * i;
        mx[c] = fmaxf(mx[c], lo); mn[c] = fminf(mn[c], lo);
        mx[c + 1] = fmaxf(mx[c + 1], hi); mn[c + 1] = fminf(mn[c + 1], hi);
      }
    }
  }
  float* ob = out + (size_t)(b * M_ + qt * 64 + q) * COUT_ + c0;
#pragma unroll
  for (int i = 0; i < 8; ++i) {
    float4 o;
#pragma unroll
    for (int e = 0; e < 4; ++e) {
      const int c = 4 * i + e;
      const float sc = scsh[c0 + c], sh = scsh[128 + c0 + c];
      const float v = sc >= 0.f ? mx[c] : mn[c];
      (&o.x)[e] = fmaf(v, sc, sh);
    }
    *(float4*)(ob + 4 * i) = o;
  }
}

extern "C" void kernel_launch(void* const* d_in, const int* in_sizes, int n_in,
                              void* d_out, int out_size, void* d_ws, size_t ws_size,
                              hipStream_t stream) {
  const float* features = (const float*)d_in[0];
  const float* positions = (const float*)d_in[1];
  const float* W = (const float*)d_in[3];
  const float* bias = (const float*)d_in[4];
  const float* gamma = (const float*)d_in[5];
  const float* beta = (const float*)d_in[6];
  float* out = (float*)d_out;
  unsigned char* ws = (unsigned char*)d_ws;

  int* fps_idx = (int*)ws;                            // 64 KB
  unsigned short* h = (unsigned short*)(ws + 65536);  // bf16, 16.8 MB
  const size_t hoff = 65536 + (size_t)B_ * N_ * COUT_ * 2;
  float* ctrl = (float*)(ws + hoff);                  // 4 KB
  u64* cand = (u64*)(ws + hoff + 4096);
  const size_t base = hoff + 4096;

  int S = 8;
  while (S > 1 && base + (size_t)B_ * M_ * S * 16 * 8 > ws_size) S >>= 1;

  const int rem = out_size - (B_ * M_ * COUT_) - (B_ * M_ * 3);
  const int batch_as_i64 = (rem >= 2 * B_ * M_) ? 1 : 0;

  hipMemsetAsync(ctrl, 0, 4096, stream);
  mega_kernel<<<B_ + 512 + 256 * S, 512, 0, stream>>>(
      positions, features, W, bias, fps_idx, h, ctrl, cand, S);
  gather_tail_kernel<<<256 + 16, 256, 0, stream>>>(
      positions, fps_idx, h, ctrl, gamma, beta, cand, out, S, batch_as_i64);
}